// Round 5
// baseline (193.923 us; speedup 1.0000x reference)
//
#include <hip/hip_runtime.h>

// Problem constants
#define T_ 128
#define B_ 64
#define NH_ 64
#define NC_ 10

__device__ __forceinline__ float sigmoid_f(float x) {
    return 1.0f / (1.0f + __expf(-x));
}
__device__ __forceinline__ float tanh_f(float x) {
    return 1.0f - 2.0f / (1.0f + __expf(2.0f * x));
}

// ---------------------------------------------------------------------------
// Kernel 1: per-frame 3x3 VALID conv -> sigmoid(logit-thr) -> spatial mean.
// grid = 8192, 256 threads. (unchanged)
// ---------------------------------------------------------------------------
#define IMP 68
__global__ __launch_bounds__(256) void conv_feat(const float* __restrict__ img,
                                                 const float* __restrict__ cw,
                                                 const float* __restrict__ cb,
                                                 const float* __restrict__ thr,
                                                 float* __restrict__ feat) {
    __shared__ __align__(16) float im[64 * IMP];
    __shared__ float wsum[4];
    const int tid = threadIdx.x;
    const float* src = img + (size_t)blockIdx.x * 4096;
#pragma unroll
    for (int i = 0; i < 4; i++) {
        const int idx = i * 256 + tid;
        const int row = idx >> 4, c4 = idx & 15;
        *(float4*)&im[row * IMP + c4 * 4] = *(const float4*)&src[idx * 4];
    }
    const float w0 = cw[0], w1 = cw[1], w2 = cw[2], w3 = cw[3], w4 = cw[4],
                w5 = cw[5], w6 = cw[6], w7 = cw[7], w8 = cw[8];
    const float bias = cb[0] - thr[0];
    __syncthreads();

    const int r  = tid >> 2;
    const int c0 = (tid & 3) * 16;
    float sum = 0.0f;
    if (r < 62) {
        const int ncols = (c0 == 48) ? 14 : 16;
        float acc[16];
#pragma unroll
        for (int x = 0; x < 16; x++) acc[x] = bias;
#pragma unroll
        for (int dr = 0; dr < 3; dr++) {
            float rb[20];
#pragma unroll
            for (int j = 0; j < 5; j++) {
                float4 v = *(const float4*)&im[(r + dr) * IMP + c0 + j * 4];
                rb[j * 4 + 0] = v.x; rb[j * 4 + 1] = v.y;
                rb[j * 4 + 2] = v.z; rb[j * 4 + 3] = v.w;
            }
            const float k0 = (dr == 0) ? w0 : (dr == 1) ? w3 : w6;
            const float k1 = (dr == 0) ? w1 : (dr == 1) ? w4 : w7;
            const float k2 = (dr == 0) ? w2 : (dr == 1) ? w5 : w8;
#pragma unroll
            for (int x = 0; x < 16; x++) {
                acc[x] = fmaf(rb[x], k0, acc[x]);
                acc[x] = fmaf(rb[x + 1], k1, acc[x]);
                acc[x] = fmaf(rb[x + 2], k2, acc[x]);
            }
        }
#pragma unroll
        for (int x = 0; x < 16; x++)
            if (x < ncols) sum += sigmoid_f(acc[x]);
    }
#pragma unroll
    for (int off = 32; off >= 1; off >>= 1) sum += __shfl_down(sum, off, 64);
    const int wv = tid >> 6, ln = tid & 63;
    if (ln == 0) wsum[wv] = sum;
    __syncthreads();
    if (tid == 0)
        feat[blockIdx.x] = (wsum[0] + wsum[1] + wsum[2] + wsum[3]) * (1.0f / 3844.0f);
}

// ---------------------------------------------------------------------------
// Kernel 2: fold fc+lw per gate (unchanged). grid = 4, 256 threads.
// ---------------------------------------------------------------------------
struct FuseArgs {
    const float* fcw[4];
    const float* fcb[4];
    const float* lw[4];
    const float* lb[4];
};

__global__ __launch_bounds__(256) void fuse_kernel(FuseArgs a, float* __restrict__ Aall,
                                                   float* __restrict__ Vall,
                                                   float* __restrict__ Call) {
    const int g = blockIdx.x;
    const float* fcw = a.fcw[g];
    const float* fcb = a.fcb[g];
    const float* lw  = a.lw[g];
    const float* lb  = a.lb[g];
    __shared__ float fcs[64 * 65];
    __shared__ float fbs[64];
    for (int i = threadIdx.x; i < 64 * 65; i += 256) fcs[i] = fcw[i];
    if (threadIdx.x < 64) fbs[threadIdx.x] = fcb[threadIdx.x];
    __syncthreads();

    const int n = threadIdx.x >> 2;
    const int j0 = (threadIdx.x & 3) * 16;
    float lrow[64];
#pragma unroll
    for (int k = 0; k < 64; k++) lrow[k] = lw[n * 64 + k];

    for (int j = j0; j < j0 + 16; j++) {
        float s = 0.0f;
#pragma unroll
        for (int k = 0; k < 64; k++) s = fmaf(lrow[k], fcs[k * 65 + j + 1], s);
        Aall[(g * 64 + n) * 64 + j] = s;
    }
    if ((threadIdx.x & 3) == 0) {
        float sv = 0.0f, sc = 0.0f;
#pragma unroll
        for (int k = 0; k < 64; k++) {
            sv = fmaf(lrow[k], fcs[k * 65], sv);
            sc = fmaf(lrow[k], fbs[k], sc);
        }
        Vall[g * 64 + n] = sv;
        Call[g * 64 + n] = sc + lb[n];
    }
}

// ---------------------------------------------------------------------------
// Kernel 3: recurrence + fused classifier. 2 batch rows per block
// (512 threads = 8 waves -> 2 waves/SIMD). Weights in named float4s,
// PINNED via opaque asm (defeats load rematerialization: VGPR was 84 across
// R1-R4 = the 128 weight floats were re-fetched every step from L2).
// waves_per_eu(2,2) pins the RA occupancy target so the 256-VGPR budget
// is actually used.
// ---------------------------------------------------------------------------
#define PIN4(v) asm volatile("" : "+v"(v.x), "+v"(v.y), "+v"(v.z), "+v"(v.w))
#define S1STEP(i) { float4 h = hp[i]; \
    a0 = fmaf(w1_##i.x, h.x, a0); a1 = fmaf(w1_##i.y, h.y, a1); \
    a2 = fmaf(w1_##i.z, h.z, a2); a3 = fmaf(w1_##i.w, h.w, a3); }
#define S2STEP(i) { float4 qv = qp[i]; \
    s0 = fmaf(w2_##i.x, qv.x, s0); s1 = fmaf(w2_##i.y, qv.y, s1); \
    s2 = fmaf(w2_##i.z, qv.z, s2); s3 = fmaf(w2_##i.w, qv.w, s3); }

__global__ __launch_bounds__(512)
__attribute__((amdgpu_waves_per_eu(2, 2)))
void recur2(
    const float* __restrict__ feat, const float* __restrict__ Aall,
    const float* __restrict__ Vall, const float* __restrict__ Call,
    const float* __restrict__ ew_f, const float* __restrict__ eb_f,
    const float* __restrict__ ew_i, const float* __restrict__ eb_i,
    const float* __restrict__ ew_u, const float* __restrict__ eb_u,
    const float* __restrict__ ew_o, const float* __restrict__ eb_o,
    const float* __restrict__ cls_w, const float* __restrict__ cls_b,
    float* __restrict__ out) {
    const int row = threadIdx.x >> 8;        // 0 or 1
    const int tid = threadIdx.x & 255;       // within-row thread
    const int b = (blockIdx.x << 1) | row;   // batch row
    const int g = tid >> 6, n = tid & 63;
    const float* ew  = (g == 0) ? ew_f : (g == 1) ? ew_i : (g == 2) ? ew_u : ew_o;
    const float* ebp = (g == 0) ? eb_f : (g == 1) ? eb_i : (g == 2) ? eb_u : eb_o;

    // --- weights in named registers, pinned against rematerialization ---
    const float4* ap = (const float4*)&Aall[tid * 64];
    const float4* ep = (const float4*)&ew[n * 64];
    float4 w1_0  = ap[0],  w1_1  = ap[1],  w1_2  = ap[2],  w1_3  = ap[3];
    float4 w1_4  = ap[4],  w1_5  = ap[5],  w1_6  = ap[6],  w1_7  = ap[7];
    float4 w1_8  = ap[8],  w1_9  = ap[9],  w1_10 = ap[10], w1_11 = ap[11];
    float4 w1_12 = ap[12], w1_13 = ap[13], w1_14 = ap[14], w1_15 = ap[15];
    float4 w2_0  = ep[0],  w2_1  = ep[1],  w2_2  = ep[2],  w2_3  = ep[3];
    float4 w2_4  = ep[4],  w2_5  = ep[5],  w2_6  = ep[6],  w2_7  = ep[7];
    float4 w2_8  = ep[8],  w2_9  = ep[9],  w2_10 = ep[10], w2_11 = ep[11];
    float4 w2_12 = ep[12], w2_13 = ep[13], w2_14 = ep[14], w2_15 = ep[15];
    PIN4(w1_0);  PIN4(w1_1);  PIN4(w1_2);  PIN4(w1_3);
    PIN4(w1_4);  PIN4(w1_5);  PIN4(w1_6);  PIN4(w1_7);
    PIN4(w1_8);  PIN4(w1_9);  PIN4(w1_10); PIN4(w1_11);
    PIN4(w1_12); PIN4(w1_13); PIN4(w1_14); PIN4(w1_15);
    PIN4(w2_0);  PIN4(w2_1);  PIN4(w2_2);  PIN4(w2_3);
    PIN4(w2_4);  PIN4(w2_5);  PIN4(w2_6);  PIN4(w2_7);
    PIN4(w2_8);  PIN4(w2_9);  PIN4(w2_10); PIN4(w2_11);
    PIN4(w2_12); PIN4(w2_13); PIN4(w2_14); PIN4(w2_15);
    const float vj = Vall[tid], cj = Call[tid], ebj = ebp[n];

    __shared__ __align__(16) float hxs[2][64];
    __shared__ __align__(16) float qs[2][256];
    __shared__ __align__(16) float acts[2][256];
    __shared__ __align__(16) float xts[2][T_];
    __shared__ __align__(16) float hist[2][T_ * 65];   // 66.6 KB
    __shared__ float cwts[NC_ * 65 + NC_];

    for (int i = tid; i < T_; i += 256) xts[row][i] = feat[b * T_ + i];
    for (int i = threadIdx.x; i < NC_ * 64; i += 512) {
        int c = i >> 6, k = i & 63;
        cwts[c * 65 + k] = cls_w[i];
    }
    if (threadIdx.x < NC_) cwts[NC_ * 65 + threadIdx.x] = cls_b[threadIdx.x];
    if (tid < 64) hxs[row][tid] = 0.0f;
    float cx = 0.0f;
    __syncthreads();

    for (int t = 0; t < T_; t++) {
        const float xt = xts[row][t];

        // stage 1: q = tanh(xt*v + h @ A^T + c)
        float a0 = 0, a1 = 0, a2 = 0, a3 = 0;
        {
            const float4* hp = (const float4*)&hxs[row][0];
            S1STEP(0)  S1STEP(1)  S1STEP(2)  S1STEP(3)
            S1STEP(4)  S1STEP(5)  S1STEP(6)  S1STEP(7)
            S1STEP(8)  S1STEP(9)  S1STEP(10) S1STEP(11)
            S1STEP(12) S1STEP(13) S1STEP(14) S1STEP(15)
        }
        const float q = tanh_f(fmaf(xt, vj, cj) + ((a0 + a1) + (a2 + a3)));
        qs[row][tid] = q;
        __syncthreads();

        // stage 2: z = q * sigmoid(q @ ew^T + eb); gate activation
        float s0 = 0, s1 = 0, s2 = 0, s3 = 0;
        {
            const float4* qp = (const float4*)&qs[row][g << 6];
            S2STEP(0)  S2STEP(1)  S2STEP(2)  S2STEP(3)
            S2STEP(4)  S2STEP(5)  S2STEP(6)  S2STEP(7)
            S2STEP(8)  S2STEP(9)  S2STEP(10) S2STEP(11)
            S2STEP(12) S2STEP(13) S2STEP(14) S2STEP(15)
        }
        const float z = q * sigmoid_f(((s0 + s1) + (s2 + s3)) + ebj);
        acts[row][tid] = (g == 2) ? tanh_f(z) : sigmoid_f(z);
        __syncthreads();

        // cell update by lanes 0..63 of wave 0 (per row)
        if (tid < 64) {
            const float ff = acts[row][tid], ii = acts[row][64 + tid],
                        uu = acts[row][128 + tid], oo = acts[row][192 + tid];
            cx = fmaf(ff, cx, ii * uu);
            const float h = oo * tanh_f(cx);
            hxs[row][tid] = h;
            hist[row][t * 65 + tid] = h;
        }
        __syncthreads();
    }

    // fused classifier: per row T_*NC_ = 1280 outputs over 256 threads
#pragma unroll
    for (int j = 0; j < 5; j++) {
        const int o = j * 256 + tid;
        const int r = o / 10;
        const int c = o - r * 10;
        float s = cwts[NC_ * 65 + c];
#pragma unroll 16
        for (int k = 0; k < 64; k++) s = fmaf(hist[row][r * 65 + k], cwts[c * 65 + k], s);
        out[((size_t)r * B_ + b) * NC_ + c] = s;
    }
}

// ---------------------------------------------------------------------------
extern "C" void kernel_launch(void* const* d_in, const int* in_sizes, int n_in,
                              void* d_out, int out_size, void* d_ws, size_t ws_size,
                              hipStream_t stream) {
    const float* images = (const float*)d_in[0];
    const float* thr    = (const float*)d_in[1];
    const float* convw  = (const float*)d_in[2];
    const float* convb  = (const float*)d_in[3];
    const float* fcw[4]; const float* fcb[4]; const float* lw[4]; const float* lb[4];
    const float* ew[4];  const float* eb[4];
    for (int g = 0; g < 4; g++) {
        int base = 4 + g * 6;
        fcw[g] = (const float*)d_in[base + 0];
        fcb[g] = (const float*)d_in[base + 1];
        lw[g]  = (const float*)d_in[base + 2];
        lb[g]  = (const float*)d_in[base + 3];
        ew[g]  = (const float*)d_in[base + 4];
        eb[g]  = (const float*)d_in[base + 5];
    }
    const float* clsw = (const float*)d_in[28];
    const float* clsb = (const float*)d_in[29];

    float* ws   = (float*)d_ws;
    float* feat = ws;            // 8192 floats
    float* Aall = ws + 8192;     // 16384 floats
    float* Vall = ws + 24576;    // 256
    float* Call = ws + 24832;    // 256

    conv_feat<<<8192, 256, 0, stream>>>(images, convw, convb, thr, feat);

    FuseArgs fa;
    for (int g = 0; g < 4; g++) {
        fa.fcw[g] = fcw[g]; fa.fcb[g] = fcb[g];
        fa.lw[g] = lw[g];   fa.lb[g] = lb[g];
    }
    fuse_kernel<<<4, 256, 0, stream>>>(fa, Aall, Vall, Call);

    recur2<<<B_ / 2, 512, 0, stream>>>(feat, Aall, Vall, Call,
                                       ew[0], eb[0], ew[1], eb[1],
                                       ew[2], eb[2], ew[3], eb[3],
                                       clsw, clsb, (float*)d_out);
}

// Round 6
// 192.504 us; speedup vs baseline: 1.0074x; 1.0074x over previous
//
#include <hip/hip_runtime.h>

// Problem constants
#define T_ 128
#define B_ 64
#define NH_ 64
#define NC_ 10

__device__ __forceinline__ float sigmoid_f(float x) {
    return 1.0f / (1.0f + __expf(-x));
}
__device__ __forceinline__ float tanh_f(float x) {
    return 1.0f - 2.0f / (1.0f + __expf(2.0f * x));
}

// ---------------------------------------------------------------------------
// Kernel 1: per-frame 3x3 VALID conv -> sigmoid(logit-thr) -> spatial mean.
// grid = 8192, 256 threads. (unchanged)
// ---------------------------------------------------------------------------
#define IMP 68
__global__ __launch_bounds__(256) void conv_feat(const float* __restrict__ img,
                                                 const float* __restrict__ cw,
                                                 const float* __restrict__ cb,
                                                 const float* __restrict__ thr,
                                                 float* __restrict__ feat) {
    __shared__ __align__(16) float im[64 * IMP];
    __shared__ float wsum[4];
    const int tid = threadIdx.x;
    const float* src = img + (size_t)blockIdx.x * 4096;
#pragma unroll
    for (int i = 0; i < 4; i++) {
        const int idx = i * 256 + tid;
        const int row = idx >> 4, c4 = idx & 15;
        *(float4*)&im[row * IMP + c4 * 4] = *(const float4*)&src[idx * 4];
    }
    const float w0 = cw[0], w1 = cw[1], w2 = cw[2], w3 = cw[3], w4 = cw[4],
                w5 = cw[5], w6 = cw[6], w7 = cw[7], w8 = cw[8];
    const float bias = cb[0] - thr[0];
    __syncthreads();

    const int r  = tid >> 2;
    const int c0 = (tid & 3) * 16;
    float sum = 0.0f;
    if (r < 62) {
        const int ncols = (c0 == 48) ? 14 : 16;
        float acc[16];
#pragma unroll
        for (int x = 0; x < 16; x++) acc[x] = bias;
#pragma unroll
        for (int dr = 0; dr < 3; dr++) {
            float rb[20];
#pragma unroll
            for (int j = 0; j < 5; j++) {
                float4 v = *(const float4*)&im[(r + dr) * IMP + c0 + j * 4];
                rb[j * 4 + 0] = v.x; rb[j * 4 + 1] = v.y;
                rb[j * 4 + 2] = v.z; rb[j * 4 + 3] = v.w;
            }
            const float k0 = (dr == 0) ? w0 : (dr == 1) ? w3 : w6;
            const float k1 = (dr == 0) ? w1 : (dr == 1) ? w4 : w7;
            const float k2 = (dr == 0) ? w2 : (dr == 1) ? w5 : w8;
#pragma unroll
            for (int x = 0; x < 16; x++) {
                acc[x] = fmaf(rb[x], k0, acc[x]);
                acc[x] = fmaf(rb[x + 1], k1, acc[x]);
                acc[x] = fmaf(rb[x + 2], k2, acc[x]);
            }
        }
#pragma unroll
        for (int x = 0; x < 16; x++)
            if (x < ncols) sum += sigmoid_f(acc[x]);
    }
#pragma unroll
    for (int off = 32; off >= 1; off >>= 1) sum += __shfl_down(sum, off, 64);
    const int wv = tid >> 6, ln = tid & 63;
    if (ln == 0) wsum[wv] = sum;
    __syncthreads();
    if (tid == 0)
        feat[blockIdx.x] = (wsum[0] + wsum[1] + wsum[2] + wsum[3]) * (1.0f / 3844.0f);
}

// ---------------------------------------------------------------------------
// Kernel 2: fold fc+lw per gate (unchanged). grid = 4, 256 threads.
// ---------------------------------------------------------------------------
struct FuseArgs {
    const float* fcw[4];
    const float* fcb[4];
    const float* lw[4];
    const float* lb[4];
};

__global__ __launch_bounds__(256) void fuse_kernel(FuseArgs a, float* __restrict__ Aall,
                                                   float* __restrict__ Vall,
                                                   float* __restrict__ Call) {
    const int g = blockIdx.x;
    const float* fcw = a.fcw[g];
    const float* fcb = a.fcb[g];
    const float* lw  = a.lw[g];
    const float* lb  = a.lb[g];
    __shared__ float fcs[64 * 65];
    __shared__ float fbs[64];
    for (int i = threadIdx.x; i < 64 * 65; i += 256) fcs[i] = fcw[i];
    if (threadIdx.x < 64) fbs[threadIdx.x] = fcb[threadIdx.x];
    __syncthreads();

    const int n = threadIdx.x >> 2;
    const int j0 = (threadIdx.x & 3) * 16;
    float lrow[64];
#pragma unroll
    for (int k = 0; k < 64; k++) lrow[k] = lw[n * 64 + k];

    for (int j = j0; j < j0 + 16; j++) {
        float s = 0.0f;
#pragma unroll
        for (int k = 0; k < 64; k++) s = fmaf(lrow[k], fcs[k * 65 + j + 1], s);
        Aall[(g * 64 + n) * 64 + j] = s;
    }
    if ((threadIdx.x & 3) == 0) {
        float sv = 0.0f, sc = 0.0f;
#pragma unroll
        for (int k = 0; k < 64; k++) {
            sv = fmaf(lrow[k], fcs[k * 65], sv);
            sc = fmaf(lrow[k], fbs[k], sc);
        }
        Vall[g * 64 + n] = sv;
        Call[g * 64 + n] = sc + lb[n];
    }
}

// ---------------------------------------------------------------------------
// Kernel 3: recurrence + fused classifier. One block per batch row
// (64 blocks x 256 threads, wave = gate, lane = hidden unit).
// The 128 loop-invariant weight floats are PARKED IN AGPRs via explicit
// v_accvgpr_write/read asm: asm results can't be rematerialized, AGPR+VGPR
// pressure (128+~80) is far under the 512 unified budget, so nothing spills.
// (R1-R5 all showed VGPR_Count 72-88 => weights were re-fetched from L2
// every step; that reload was ~60% of the 2700-cycle step.)
// One barrier per step: per-wave private hxs/qs, redundant cell update,
// double-buffered acts exchange.
// ---------------------------------------------------------------------------
#define PARKW(a_, v_) asm volatile("v_accvgpr_write_b32 %0, %1" : "=a"(a_) : "v"(v_))
#define READW(v_, a_) asm volatile("v_accvgpr_read_b32 %0, %1" : "=v"(v_) : "a"(a_))
#define DECLP4(nm) float nm##_x, nm##_y, nm##_z, nm##_w
#define PARK4(nm, vec) PARKW(nm##_x, (vec).x); PARKW(nm##_y, (vec).y); \
                       PARKW(nm##_z, (vec).z); PARKW(nm##_w, (vec).w)
// one 4-wide chunk of the stage-1 matvec: read 4 weights from AGPR, fma with h
#define S1G(i) { float u0, u1, u2, u3; \
    READW(u0, p1_##i##_x); READW(u1, p1_##i##_y); \
    READW(u2, p1_##i##_z); READW(u3, p1_##i##_w); \
    a0 = fmaf(u0, hv##i.x, a0); a1 = fmaf(u1, hv##i.y, a1); \
    a2 = fmaf(u2, hv##i.z, a2); a3 = fmaf(u3, hv##i.w, a3); }
#define S2G(i) { float u0, u1, u2, u3; \
    READW(u0, p2_##i##_x); READW(u1, p2_##i##_y); \
    READW(u2, p2_##i##_z); READW(u3, p2_##i##_w); \
    s0 = fmaf(u0, qv##i.x, s0); s1 = fmaf(u1, qv##i.y, s1); \
    s2 = fmaf(u2, qv##i.z, s2); s3 = fmaf(u3, qv##i.w, s3); }

__global__ __launch_bounds__(256, 1) void recur(
    const float* __restrict__ feat, const float* __restrict__ Aall,
    const float* __restrict__ Vall, const float* __restrict__ Call,
    const float* __restrict__ ew_f, const float* __restrict__ eb_f,
    const float* __restrict__ ew_i, const float* __restrict__ eb_i,
    const float* __restrict__ ew_u, const float* __restrict__ eb_u,
    const float* __restrict__ ew_o, const float* __restrict__ eb_o,
    const float* __restrict__ cls_w, const float* __restrict__ cls_b,
    float* __restrict__ out) {
    const int b = blockIdx.x;
    const int tid = threadIdx.x;
    const int g = tid >> 6, n = tid & 63;
    const float* ew  = (g == 0) ? ew_f : (g == 1) ? ew_i : (g == 2) ? ew_u : ew_o;
    const float* ebp = (g == 0) ? eb_f : (g == 1) ? eb_i : (g == 2) ? eb_u : eb_o;

    // --- park 128 weight floats in AGPRs ---
    DECLP4(p1_0);  DECLP4(p1_1);  DECLP4(p1_2);  DECLP4(p1_3);
    DECLP4(p1_4);  DECLP4(p1_5);  DECLP4(p1_6);  DECLP4(p1_7);
    DECLP4(p1_8);  DECLP4(p1_9);  DECLP4(p1_10); DECLP4(p1_11);
    DECLP4(p1_12); DECLP4(p1_13); DECLP4(p1_14); DECLP4(p1_15);
    DECLP4(p2_0);  DECLP4(p2_1);  DECLP4(p2_2);  DECLP4(p2_3);
    DECLP4(p2_4);  DECLP4(p2_5);  DECLP4(p2_6);  DECLP4(p2_7);
    DECLP4(p2_8);  DECLP4(p2_9);  DECLP4(p2_10); DECLP4(p2_11);
    DECLP4(p2_12); DECLP4(p2_13); DECLP4(p2_14); DECLP4(p2_15);
    {
        const float4* ap = (const float4*)&Aall[tid * 64];
        const float4* ep = (const float4*)&ew[n * 64];
        float4 tv;
        tv = ap[0];  PARK4(p1_0, tv);   tv = ap[1];  PARK4(p1_1, tv);
        tv = ap[2];  PARK4(p1_2, tv);   tv = ap[3];  PARK4(p1_3, tv);
        tv = ap[4];  PARK4(p1_4, tv);   tv = ap[5];  PARK4(p1_5, tv);
        tv = ap[6];  PARK4(p1_6, tv);   tv = ap[7];  PARK4(p1_7, tv);
        tv = ap[8];  PARK4(p1_8, tv);   tv = ap[9];  PARK4(p1_9, tv);
        tv = ap[10]; PARK4(p1_10, tv);  tv = ap[11]; PARK4(p1_11, tv);
        tv = ap[12]; PARK4(p1_12, tv);  tv = ap[13]; PARK4(p1_13, tv);
        tv = ap[14]; PARK4(p1_14, tv);  tv = ap[15]; PARK4(p1_15, tv);
        tv = ep[0];  PARK4(p2_0, tv);   tv = ep[1];  PARK4(p2_1, tv);
        tv = ep[2];  PARK4(p2_2, tv);   tv = ep[3];  PARK4(p2_3, tv);
        tv = ep[4];  PARK4(p2_4, tv);   tv = ep[5];  PARK4(p2_5, tv);
        tv = ep[6];  PARK4(p2_6, tv);   tv = ep[7];  PARK4(p2_7, tv);
        tv = ep[8];  PARK4(p2_8, tv);   tv = ep[9];  PARK4(p2_9, tv);
        tv = ep[10]; PARK4(p2_10, tv);  tv = ep[11]; PARK4(p2_11, tv);
        tv = ep[12]; PARK4(p2_12, tv);  tv = ep[13]; PARK4(p2_13, tv);
        tv = ep[14]; PARK4(p2_14, tv);  tv = ep[15]; PARK4(p2_15, tv);
    }
    const float vj = Vall[tid], cj = Call[tid], ebj = ebp[n];

    __shared__ __align__(16) float hxs[4][64];      // per-wave private copy
    __shared__ __align__(16) float qs[4][64];       // per-wave private
    __shared__ __align__(16) float acts[2][4][64];  // double-buffered exchange
    __shared__ float xts[T_];
    __shared__ float hist[T_ * 65];                 // padded h history (33 KB)
    __shared__ float cwts[NC_ * 65 + NC_];

    for (int i = tid; i < T_; i += 256) xts[i] = feat[b * T_ + i];
    for (int i = tid; i < NC_ * 64; i += 256) {
        int c = i >> 6, k = i & 63;
        cwts[c * 65 + k] = cls_w[i];
    }
    if (tid < NC_) cwts[NC_ * 65 + tid] = cls_b[tid];
    hxs[g][n] = 0.0f;
    float cx = 0.0f;
    __syncthreads();

    const float4* hp = (const float4*)&hxs[g][0];
    const float4* qp = (const float4*)&qs[g][0];

    for (int t = 0; t < T_; t++) {
        const float xt = xts[t];

        // stage 1: q = tanh(xt*v + h @ A^T + c) — weights from AGPR
        float4 hv0 = hp[0],  hv1 = hp[1],  hv2 = hp[2],  hv3 = hp[3];
        float4 hv4 = hp[4],  hv5 = hp[5],  hv6 = hp[6],  hv7 = hp[7];
        float4 hv8 = hp[8],  hv9 = hp[9],  hv10 = hp[10], hv11 = hp[11];
        float4 hv12 = hp[12], hv13 = hp[13], hv14 = hp[14], hv15 = hp[15];
        float a0 = 0, a1 = 0, a2 = 0, a3 = 0;
        S1G(0)  S1G(1)  S1G(2)  S1G(3)  S1G(4)  S1G(5)  S1G(6)  S1G(7)
        S1G(8)  S1G(9)  S1G(10) S1G(11) S1G(12) S1G(13) S1G(14) S1G(15)
        const float q = tanh_f(fmaf(xt, vj, cj) + ((a0 + a1) + (a2 + a3)));
        qs[g][n] = q;  // own-wave exchange; compiler inserts the lgkm wait

        // stage 2: z = q * sigmoid(q @ ew^T + eb)
        float4 qv0 = qp[0],  qv1 = qp[1],  qv2 = qp[2],  qv3 = qp[3];
        float4 qv4 = qp[4],  qv5 = qp[5],  qv6 = qp[6],  qv7 = qp[7];
        float4 qv8 = qp[8],  qv9 = qp[9],  qv10 = qp[10], qv11 = qp[11];
        float4 qv12 = qp[12], qv13 = qp[13], qv14 = qp[14], qv15 = qp[15];
        float s0 = 0, s1 = 0, s2 = 0, s3 = 0;
        S2G(0)  S2G(1)  S2G(2)  S2G(3)  S2G(4)  S2G(5)  S2G(6)  S2G(7)
        S2G(8)  S2G(9)  S2G(10) S2G(11) S2G(12) S2G(13) S2G(14) S2G(15)
        const float z = q * sigmoid_f(((s0 + s1) + (s2 + s3)) + ebj);
        acts[t & 1][g][n] = (g == 2) ? tanh_f(z) : sigmoid_f(z);
        __syncthreads();  // the ONLY barrier per step

        // cell update — redundantly on all 4 waves (bitwise identical)
        const float ff = acts[t & 1][0][n];
        const float ii = acts[t & 1][1][n];
        const float uu = acts[t & 1][2][n];
        const float oo = acts[t & 1][3][n];
        cx = fmaf(ff, cx, ii * uu);
        const float h = oo * tanh_f(cx);
        hxs[g][n] = h;                       // own wave's copy for next step
        if (g == 0) hist[t * 65 + n] = h;
    }
    __syncthreads();  // hist complete

    // fused classifier: T_*NC_ = 1280 outputs over 256 threads
#pragma unroll
    for (int j = 0; j < 5; j++) {
        const int o = j * 256 + tid;
        const int r = o / 10;
        const int c = o - r * 10;
        float s = cwts[NC_ * 65 + c];
#pragma unroll 16
        for (int k = 0; k < 64; k++) s = fmaf(hist[r * 65 + k], cwts[c * 65 + k], s);
        out[((size_t)r * B_ + b) * NC_ + c] = s;
    }
}

// ---------------------------------------------------------------------------
extern "C" void kernel_launch(void* const* d_in, const int* in_sizes, int n_in,
                              void* d_out, int out_size, void* d_ws, size_t ws_size,
                              hipStream_t stream) {
    const float* images = (const float*)d_in[0];
    const float* thr    = (const float*)d_in[1];
    const float* convw  = (const float*)d_in[2];
    const float* convb  = (const float*)d_in[3];
    const float* fcw[4]; const float* fcb[4]; const float* lw[4]; const float* lb[4];
    const float* ew[4];  const float* eb[4];
    for (int g = 0; g < 4; g++) {
        int base = 4 + g * 6;
        fcw[g] = (const float*)d_in[base + 0];
        fcb[g] = (const float*)d_in[base + 1];
        lw[g]  = (const float*)d_in[base + 2];
        lb[g]  = (const float*)d_in[base + 3];
        ew[g]  = (const float*)d_in[base + 4];
        eb[g]  = (const float*)d_in[base + 5];
    }
    const float* clsw = (const float*)d_in[28];
    const float* clsb = (const float*)d_in[29];

    float* ws   = (float*)d_ws;
    float* feat = ws;            // 8192 floats
    float* Aall = ws + 8192;     // 16384 floats
    float* Vall = ws + 24576;    // 256
    float* Call = ws + 24832;    // 256

    conv_feat<<<8192, 256, 0, stream>>>(images, convw, convb, thr, feat);

    FuseArgs fa;
    for (int g = 0; g < 4; g++) {
        fa.fcw[g] = fcw[g]; fa.fcb[g] = fcb[g];
        fa.lw[g] = lw[g];   fa.lb[g] = lb[g];
    }
    fuse_kernel<<<4, 256, 0, stream>>>(fa, Aall, Vall, Call);

    recur<<<B_, 256, 0, stream>>>(feat, Aall, Vall, Call,
                                  ew[0], eb[0], ew[1], eb[1],
                                  ew[2], eb[2], ew[3], eb[3],
                                  clsw, clsb, (float*)d_out);
}

// Round 9
// 163.533 us; speedup vs baseline: 1.1858x; 1.1772x over previous
//
#include <hip/hip_runtime.h>

// Problem constants
#define T_ 128
#define B_ 64
#define NH_ 64
#define NC_ 10

__device__ __forceinline__ float sigmoid_f(float x) {
    return 1.0f / (1.0f + __expf(-x));
}
__device__ __forceinline__ float tanh_f(float x) {
    return 1.0f - 2.0f / (1.0f + __expf(2.0f * x));
}
// 4-wide partial dot accumulate (inline fn, not macro: '.w' member access
// collides with macro params — R8 compile failure)
__device__ __forceinline__ void dot4(const float4 a, const float4 v,
                                     float& p0, float& p1, float& p2, float& p3) {
    p0 = fmaf(a.x, v.x, p0);
    p1 = fmaf(a.y, v.y, p1);
    p2 = fmaf(a.z, v.z, p2);
    p3 = fmaf(a.w, v.w, p3);
}

// ---------------------------------------------------------------------------
// Kernel 1: per-frame 3x3 VALID conv -> sigmoid(logit-thr) -> spatial mean.
// grid = 8192, 256 threads. (unchanged)
// ---------------------------------------------------------------------------
#define IMP 68
__global__ __launch_bounds__(256) void conv_feat(const float* __restrict__ img,
                                                 const float* __restrict__ cw,
                                                 const float* __restrict__ cb,
                                                 const float* __restrict__ thr,
                                                 float* __restrict__ feat) {
    __shared__ __align__(16) float im[64 * IMP];
    __shared__ float wsum[4];
    const int tid = threadIdx.x;
    const float* src = img + (size_t)blockIdx.x * 4096;
#pragma unroll
    for (int i = 0; i < 4; i++) {
        const int idx = i * 256 + tid;
        const int row = idx >> 4, c4 = idx & 15;
        *(float4*)&im[row * IMP + c4 * 4] = *(const float4*)&src[idx * 4];
    }
    const float w0 = cw[0], w1 = cw[1], w2 = cw[2], w3 = cw[3], w4 = cw[4],
                w5 = cw[5], w6 = cw[6], w7 = cw[7], w8 = cw[8];
    const float bias = cb[0] - thr[0];
    __syncthreads();

    const int r  = tid >> 2;
    const int c0 = (tid & 3) * 16;
    float sum = 0.0f;
    if (r < 62) {
        const int ncols = (c0 == 48) ? 14 : 16;
        float acc[16];
#pragma unroll
        for (int x = 0; x < 16; x++) acc[x] = bias;
#pragma unroll
        for (int dr = 0; dr < 3; dr++) {
            float rb[20];
#pragma unroll
            for (int j = 0; j < 5; j++) {
                float4 v = *(const float4*)&im[(r + dr) * IMP + c0 + j * 4];
                rb[j * 4 + 0] = v.x; rb[j * 4 + 1] = v.y;
                rb[j * 4 + 2] = v.z; rb[j * 4 + 3] = v.w;
            }
            const float k0 = (dr == 0) ? w0 : (dr == 1) ? w3 : w6;
            const float k1 = (dr == 0) ? w1 : (dr == 1) ? w4 : w7;
            const float k2 = (dr == 0) ? w2 : (dr == 1) ? w5 : w8;
#pragma unroll
            for (int x = 0; x < 16; x++) {
                acc[x] = fmaf(rb[x], k0, acc[x]);
                acc[x] = fmaf(rb[x + 1], k1, acc[x]);
                acc[x] = fmaf(rb[x + 2], k2, acc[x]);
            }
        }
#pragma unroll
        for (int x = 0; x < 16; x++)
            if (x < ncols) sum += sigmoid_f(acc[x]);
    }
#pragma unroll
    for (int off = 32; off >= 1; off >>= 1) sum += __shfl_down(sum, off, 64);
    const int wv = tid >> 6, ln = tid & 63;
    if (ln == 0) wsum[wv] = sum;
    __syncthreads();
    if (tid == 0)
        feat[blockIdx.x] = (wsum[0] + wsum[1] + wsum[2] + wsum[3]) * (1.0f / 3844.0f);
}

// ---------------------------------------------------------------------------
// Kernel 2: fold fc+lw per gate (unchanged). grid = 4, 256 threads.
// ---------------------------------------------------------------------------
struct FuseArgs {
    const float* fcw[4];
    const float* fcb[4];
    const float* lw[4];
    const float* lb[4];
};

__global__ __launch_bounds__(256) void fuse_kernel(FuseArgs a, float* __restrict__ Aall,
                                                   float* __restrict__ Vall,
                                                   float* __restrict__ Call) {
    const int g = blockIdx.x;
    const float* fcw = a.fcw[g];
    const float* fcb = a.fcb[g];
    const float* lw  = a.lw[g];
    const float* lb  = a.lb[g];
    __shared__ float fcs[64 * 65];
    __shared__ float fbs[64];
    for (int i = threadIdx.x; i < 64 * 65; i += 256) fcs[i] = fcw[i];
    if (threadIdx.x < 64) fbs[threadIdx.x] = fcb[threadIdx.x];
    __syncthreads();

    const int n = threadIdx.x >> 2;
    const int j0 = (threadIdx.x & 3) * 16;
    float lrow[64];
#pragma unroll
    for (int k = 0; k < 64; k++) lrow[k] = lw[n * 64 + k];

    for (int j = j0; j < j0 + 16; j++) {
        float s = 0.0f;
#pragma unroll
        for (int k = 0; k < 64; k++) s = fmaf(lrow[k], fcs[k * 65 + j + 1], s);
        Aall[(g * 64 + n) * 64 + j] = s;
    }
    if ((threadIdx.x & 3) == 0) {
        float sv = 0.0f, sc = 0.0f;
#pragma unroll
        for (int k = 0; k < 64; k++) {
            sv = fmaf(lrow[k], fcs[k * 65], sv);
            sc = fmaf(lrow[k], fbs[k], sc);
        }
        Vall[g * 64 + n] = sv;
        Call[g * 64 + n] = sc + lb[n];
    }
}

// ---------------------------------------------------------------------------
// Kernel 3: recurrence + fused classifier, SPLIT-K=2.
// 64 blocks (one per batch row) x 512 threads = 8 waves = 2 waves/SIMD.
// wave = (gate g, n-half nh); lane = (n&31) | (k-half s)<<5.
// Thread owns output n = nh*32+(lane&31), computes a 32-wide partial dot
// (half of before), completes it with one intra-wave __shfl_xor(.,32).
// Cell update redundant per-thread. 3 barriers per step.
// ---------------------------------------------------------------------------
__global__ __launch_bounds__(512, 1) void recur(
    const float* __restrict__ feat, const float* __restrict__ Aall,
    const float* __restrict__ Vall, const float* __restrict__ Call,
    const float* __restrict__ ew_f, const float* __restrict__ eb_f,
    const float* __restrict__ ew_i, const float* __restrict__ eb_i,
    const float* __restrict__ ew_u, const float* __restrict__ eb_u,
    const float* __restrict__ ew_o, const float* __restrict__ eb_o,
    const float* __restrict__ cls_w, const float* __restrict__ cls_b,
    float* __restrict__ out) {
    const int b = blockIdx.x;
    const int tid = threadIdx.x;
    const int wave = tid >> 6;
    const int g = wave >> 1;              // gate 0..3
    const int nh = wave & 1;              // n-half 0..1
    const int lane = tid & 63;
    const int s = lane >> 5;              // k-half 0..1
    const int n = nh * 32 + (lane & 31);  // owned output/hidden index
    const int gn = g * 64 + n;
    const float* ew  = (g == 0) ? ew_f : (g == 1) ? ew_i : (g == 2) ? ew_u : ew_o;
    const float* ebp = (g == 0) ? eb_f : (g == 1) ? eb_i : (g == 2) ? eb_u : eb_o;

    // weight slices (32 floats each) in named float4s; R4/R6 proved the
    // compiler's per-step reloads of these pipeline for free.
    const float4* ap = (const float4*)&Aall[gn * 64 + s * 32];
    const float4* ep = (const float4*)&ew[n * 64 + s * 32];
    const float4 wa0 = ap[0], wa1 = ap[1], wa2 = ap[2], wa3 = ap[3];
    const float4 wa4 = ap[4], wa5 = ap[5], wa6 = ap[6], wa7 = ap[7];
    const float4 we0 = ep[0], we1 = ep[1], we2 = ep[2], we3 = ep[3];
    const float4 we4 = ep[4], we5 = ep[5], we6 = ep[6], we7 = ep[7];
    const float vj = Vall[gn], cj = Call[gn], ebj = ebp[n];

    __shared__ __align__(16) float hx[64];
    __shared__ __align__(16) float qsh[4][64];
    __shared__ __align__(16) float acts[2][4][64];
    __shared__ __align__(16) float xts[T_];
    __shared__ float hist[T_ * 65];              // 33.3 KB
    __shared__ float cwts[NC_ * 65 + NC_];

    for (int i = tid; i < T_; i += 512) xts[i] = feat[b * T_ + i];
    for (int i = tid; i < NC_ * 64; i += 512) {
        int c = i >> 6, k = i & 63;
        cwts[c * 65 + k] = cls_w[i];
    }
    if (tid < NC_) cwts[NC_ * 65 + tid] = cls_b[tid];
    if (tid < 64) hx[tid] = 0.0f;
    float cx = 0.0f;   // cell state for unit n, replicated across waves
    __syncthreads();

    const float4* hp = (const float4*)&hx[s * 32];
    const float4* qp = (const float4*)&qsh[g][s * 32];

    for (int t = 0; t < T_; t++) {
        const float xt = xts[t];

        // ---- stage 1: q = tanh(xt*v + h @ A^T + c), split-K over s ----
        float p0 = 0, p1 = 0, p2 = 0, p3 = 0;
        {
            float4 v0 = hp[0], v1 = hp[1], v2 = hp[2], v3 = hp[3];
            float4 v4 = hp[4], v5 = hp[5], v6 = hp[6], v7 = hp[7];
            dot4(wa0, v0, p0, p1, p2, p3);
            dot4(wa1, v1, p0, p1, p2, p3);
            dot4(wa2, v2, p0, p1, p2, p3);
            dot4(wa3, v3, p0, p1, p2, p3);
            dot4(wa4, v4, p0, p1, p2, p3);
            dot4(wa5, v5, p0, p1, p2, p3);
            dot4(wa6, v6, p0, p1, p2, p3);
            dot4(wa7, v7, p0, p1, p2, p3);
        }
        float p = (p0 + p1) + (p2 + p3);
        p += __shfl_xor(p, 32, 64);                 // combine the two k-halves
        const float q = tanh_f(fmaf(xt, vj, cj) + p);
        if (s == 0) qsh[g][n] = q;
        __syncthreads();                            // barrier 1 (q exchange)

        // ---- stage 2: z = q * sigmoid(q @ ew^T + eb), split-K over s ----
        p0 = 0; p1 = 0; p2 = 0; p3 = 0;
        {
            float4 v0 = qp[0], v1 = qp[1], v2 = qp[2], v3 = qp[3];
            float4 v4 = qp[4], v5 = qp[5], v6 = qp[6], v7 = qp[7];
            dot4(we0, v0, p0, p1, p2, p3);
            dot4(we1, v1, p0, p1, p2, p3);
            dot4(we2, v2, p0, p1, p2, p3);
            dot4(we3, v3, p0, p1, p2, p3);
            dot4(we4, v4, p0, p1, p2, p3);
            dot4(we5, v5, p0, p1, p2, p3);
            dot4(we6, v6, p0, p1, p2, p3);
            dot4(we7, v7, p0, p1, p2, p3);
        }
        p = (p0 + p1) + (p2 + p3);
        p += __shfl_xor(p, 32, 64);
        const float z = q * sigmoid_f(p + ebj);
        const float act = (g == 2) ? tanh_f(z) : sigmoid_f(z);
        if (s == 0) acts[t & 1][g][n] = act;
        __syncthreads();                            // barrier 2 (acts exchange)

        // ---- cell update: every thread, own n, redundant across waves ----
        const float ff = acts[t & 1][0][n];
        const float ii = acts[t & 1][1][n];
        const float uu = acts[t & 1][2][n];
        const float oo = acts[t & 1][3][n];
        cx = fmaf(ff, cx, ii * uu);
        const float h = oo * tanh_f(cx);
        if (wave < 2 && s == 0) {                   // waves 0,1 cover n=0..63
            hx[n] = h;
            hist[t * 65 + n] = h;
        }
        __syncthreads();                            // barrier 3 (h exchange)
    }

    // fused classifier: T_*NC_ = 1280 outputs over 512 threads
#pragma unroll
    for (int j = 0; j < 3; j++) {
        const int o = j * 512 + tid;
        if (o < T_ * NC_) {
            const int r = o / 10;
            const int c = o - r * 10;
            float sacc = cwts[NC_ * 65 + c];
#pragma unroll 16
            for (int k = 0; k < 64; k++)
                sacc = fmaf(hist[r * 65 + k], cwts[c * 65 + k], sacc);
            out[((size_t)r * B_ + b) * NC_ + c] = sacc;
        }
    }
}

// ---------------------------------------------------------------------------
extern "C" void kernel_launch(void* const* d_in, const int* in_sizes, int n_in,
                              void* d_out, int out_size, void* d_ws, size_t ws_size,
                              hipStream_t stream) {
    const float* images = (const float*)d_in[0];
    const float* thr    = (const float*)d_in[1];
    const float* convw  = (const float*)d_in[2];
    const float* convb  = (const float*)d_in[3];
    const float* fcw[4]; const float* fcb[4]; const float* lw[4]; const float* lb[4];
    const float* ew[4];  const float* eb[4];
    for (int g = 0; g < 4; g++) {
        int base = 4 + g * 6;
        fcw[g] = (const float*)d_in[base + 0];
        fcb[g] = (const float*)d_in[base + 1];
        lw[g]  = (const float*)d_in[base + 2];
        lb[g]  = (const float*)d_in[base + 3];
        ew[g]  = (const float*)d_in[base + 4];
        eb[g]  = (const float*)d_in[base + 5];
    }
    const float* clsw = (const float*)d_in[28];
    const float* clsb = (const float*)d_in[29];

    float* ws   = (float*)d_ws;
    float* feat = ws;            // 8192 floats
    float* Aall = ws + 8192;     // 16384 floats
    float* Vall = ws + 24576;    // 256
    float* Call = ws + 24832;    // 256

    conv_feat<<<8192, 256, 0, stream>>>(images, convw, convb, thr, feat);

    FuseArgs fa;
    for (int g = 0; g < 4; g++) {
        fa.fcw[g] = fcw[g]; fa.fcb[g] = fcb[g];
        fa.lw[g] = lw[g];   fa.lb[g] = lb[g];
    }
    fuse_kernel<<<4, 256, 0, stream>>>(fa, Aall, Vall, Call);

    recur<<<B_, 512, 0, stream>>>(feat, Aall, Vall, Call,
                                  ew[0], eb[0], ew[1], eb[1],
                                  ew[2], eb[2], ew[3], eb[3],
                                  clsw, clsb, (float*)d_out);
}